// Round 18
// baseline (118.998 us; speedup 1.0000x reference)
//
#include <hip/hip_runtime.h>

typedef unsigned short u16;
typedef unsigned int u32;

typedef __attribute__((ext_vector_type(8))) short bfrag;   // 8 bf16 for MFMA A/B
typedef __attribute__((ext_vector_type(4))) float f32x4;
typedef __attribute__((ext_vector_type(8))) u16 u16x8;
typedef __attribute__((ext_vector_type(4))) u16 u16x4;

constexpr int S = 2048;
constexpr int HN = 16;
constexpr float QSCALE = 0.18033688011112042f;  // 0.125 * log2(e)
constexpr float NBIG   = -1.442695e9f;          // -1e9 * log2(e)

__device__ __forceinline__ u16 f2b(float f) {
  u32 u = __builtin_bit_cast(u32, f);
  return (u16)((u + 0x7FFFu + ((u >> 16) & 1u)) >> 16);  // RNE f32->bf16
}
__device__ __forceinline__ float b2f(u16 v) {
  u32 u = (u32)v << 16;
  return __builtin_bit_cast(float, u);
}
__device__ __forceinline__ u32 cvtpk(float lo, float hi) {
  u32 d;
  asm("v_cvt_pk_bf16_f32 %0, %1, %2" : "=v"(d) : "v"(lo), "v"(hi));
  return d;
}
__device__ __forceinline__ float fexp2(float x) { return __builtin_amdgcn_exp2f(x); }

__device__ __forceinline__ f32x4 mfma16(bfrag a, bfrag b, f32x4 c) {
  return __builtin_amdgcn_mfma_f32_16x16x32_bf16(a, b, c, 0, 0, 0);
}

__device__ __forceinline__ void gload_lds16(const void* g, void* l) {
  __builtin_amdgcn_global_load_lds(
      (const __attribute__((address_space(1))) u32*)g,
      (__attribute__((address_space(3))) u32*)l, 16, 0, 0);
}

// ------- W transpose + f32->bf16 (+ exp2 scale for Wq); z==4 hosts the pad prescan ------
__global__ __launch_bounds__(256) void wtrans_kernel(
    const float* __restrict__ W0, const float* __restrict__ W1,
    const float* __restrict__ W2, const float* __restrict__ W3,
    u16* __restrict__ ws,
    const int* __restrict__ pad, u16* __restrict__ idxc, u16* __restrict__ posT,
    int* __restrict__ eqt, float* __restrict__ colsumg)
{
  __shared__ u16 tile[64 * 65];
  const int t = threadIdx.x;

  if (blockIdx.z == 4) {
    // ---- pad prefix-scan path (2 active blocks) ----
    if (blockIdx.y != 0 || blockIdx.x >= 2) return;
    int* wtot = (int*)tile;        // alias shared
    int* cntS = (int*)tile + 4;
    const int b = blockIdx.x;
    const int lane = t & 63, w = t >> 6;
    for (int i = t; i < 1024; i += 256) colsumg[b * 1024 + i] = 0.f;
    int4 p0 = *(const int4*)&pad[b * 2048 + t * 8];
    int4 p1 = *(const int4*)&pad[b * 2048 + t * 8 + 4];
    int u[8] = {p0.x == 0, p0.y == 0, p0.z == 0, p0.w == 0,
                p1.x == 0, p1.y == 0, p1.z == 0, p1.w == 0};
    int ps[8], run = 0;
#pragma unroll
    for (int j = 0; j < 8; ++j) { run += u[j]; ps[j] = run; }
    int sc = run;
#pragma unroll
    for (int o = 1; o < 64; o <<= 1) {
      int v = __shfl_up(sc, o);
      if (lane >= o) sc += v;
    }
    if (lane == 63) wtot[w] = sc;
    __syncthreads();
    int base = 0;
#pragma unroll
    for (int i = 0; i < 4; ++i) if (i < w) base += wtot[i];
    int excl = base + sc - run;
#pragma unroll
    for (int j = 0; j < 8; ++j)
      if (u[j]) idxc[b * 2048 + excl + ps[j] - 1] = (u16)(t * 8 + j);
    if ((t & 7) == 7) eqt[b * 32 + (t >> 3)] = base + sc;
    if (t == 255) *cntS = base + sc;
    __syncthreads();
    const int cnt = *cntS;
#pragma unroll
    for (int j = 0; j < 8; ++j) {
      int e = t * 8 + j;
      int pv = u[j] ? (excl + ps[j] - 1) : (cnt + e - excl - ps[j]);
      posT[b * 2048 + e] = (u16)pv;
    }
    for (int j = cnt + t; j < 2048; j += 256) idxc[b * 2048 + j] = 0x7FFF;
    return;
  }

  // ---- W transpose path ----
  const float* W = blockIdx.z == 0 ? W0 : blockIdx.z == 1 ? W1 : blockIdx.z == 2 ? W2 : W3;
  const float sc = blockIdx.z == 0 ? QSCALE : 1.0f;
  u16* WT = ws + (size_t)blockIdx.z * (1u << 20);
  const int k0 = blockIdx.y * 64, n0 = blockIdx.x * 64;
#pragma unroll
  for (int i = 0; i < 4; ++i) {
    int idx = i * 256 + t;
    int r = idx >> 4, c4 = (idx & 15) * 4;
    float4 v = *(const float4*)&W[(size_t)(k0 + r) * 1024 + n0 + c4];
    tile[r * 65 + c4 + 0] = f2b(v.x * sc);
    tile[r * 65 + c4 + 1] = f2b(v.y * sc);
    tile[r * 65 + c4 + 2] = f2b(v.z * sc);
    tile[r * 65 + c4 + 3] = f2b(v.w * sc);
  }
  __syncthreads();
#pragma unroll
  for (int i = 0; i < 2; ++i) {
    int idx = i * 256 + t;
    int n = idx >> 3, k8 = (idx & 7) * 8;
    u16x8 o;
#pragma unroll
    for (int j = 0; j < 8; ++j) o[j] = tile[(k8 + j) * 65 + n];
    *(u16x8*)&WT[(size_t)(n0 + n) * 1024 + k0 + k8] = o;
  }
}

// --------- f32 -> bf16 convert; K (z==1) written ROW-COMPACTED via posT ----------
__global__ __launch_bounds__(256) void cvt_kernel(
    const float* __restrict__ A0, const float* __restrict__ A1,
    const float* __restrict__ A2, const u16* __restrict__ posT,
    u16* __restrict__ outbase)
{
  const int z = blockIdx.y;
  const float* A = z == 0 ? A0 : z == 1 ? A1 : A2;
  u16* dst = outbase + (size_t)z * (4u << 20);
  const int t = threadIdx.x;
  const int row = blockIdx.x * 2 + (t >> 7);
  const int col = (t & 127) * 8;
  int drow = row;
  if (z == 1) {
    int b = row >> 11;
    drow = b * 2048 + posT[row];
  }
  const float* src = &A[(size_t)row * 1024 + col];
  float4 v0 = *(const float4*)src;
  float4 v1 = *(const float4*)(src + 4);
  union { u32 w[4]; u16x8 v; } o;
  o.w[0] = cvtpk(v0.x, v0.y); o.w[1] = cvtpk(v0.z, v0.w);
  o.w[2] = cvtpk(v1.x, v1.y); o.w[3] = cvtpk(v1.z, v1.w);
  *(u16x8*)&dst[(size_t)drow * 1024 + col] = o.v;
}

// ------- shared GEMM core, 128(M) x 64(N) tile (two-barrier structure) ----------
// CMODE 0: scatter bf16 to [B,H,S,64]; kswz -> bake attn K-staging swizzle.
// CMODE 1: f32 linear [M,N].
// CMODE 2: V path -> transposed/permuted/swizzled scatter into vTc + column sums.
template <int CMODE>
__device__ __forceinline__ void gemm_core(
    u16* As, u16* Bs,
    const u16* __restrict__ A, const u16* __restrict__ Bt,
    const float* __restrict__ bias, void* __restrict__ Cout,
    int N, int K, int bn, int bm, float bscale,
    int kswz, const u16* __restrict__ posT, float* __restrict__ csum)
{
  const int tid = threadIdx.x;
  const int wid = tid >> 6, lane = tid & 63;
  const int g = lane >> 4, c = lane & 15;
  const int wr = wid >> 1, wc = wid & 1;

  f32x4 acc[4][2] = {};

  const int nkt = K >> 6;
  for (int kt = 0; kt < nkt; ++kt) {
#pragma unroll
    for (int p = 0; p < 4; ++p) {
      int off = (p * 4 + wid) * 1024 + (lane << 4);
      int row = off >> 7, colb = off & 127;
      gload_lds16(&A[(size_t)(bm * 128 + row) * K + kt * 64 +
                     ((colb ^ ((row & 7) << 4)) >> 1)],
                  (char*)As + (p * 4 + wid) * 1024);
    }
#pragma unroll
    for (int p = 0; p < 2; ++p) {
      int off = (p * 4 + wid) * 1024 + (lane << 4);
      int row = off >> 7, colb = off & 127;
      gload_lds16(&Bt[(size_t)(bn * 64 + row) * K + kt * 64 +
                      ((colb ^ ((row & 7) << 4)) >> 1)],
                  (char*)Bs + (p * 4 + wid) * 1024);
    }
    __syncthreads();

#pragma unroll
    for (int ks = 0; ks < 2; ++ks) {
      bfrag af[4], bf[2];
#pragma unroll
      for (int mi = 0; mi < 4; ++mi) {
        int row = wr * 64 + mi * 16 + c;
        af[mi] = *(const bfrag*)&As[row * 64 + ((ks * 32 + g * 8) ^ ((row & 7) << 3))];
      }
#pragma unroll
      for (int ni = 0; ni < 2; ++ni) {
        int row = wc * 32 + ni * 16 + c;
        bf[ni] = *(const bfrag*)&Bs[row * 64 + ((ks * 32 + g * 8) ^ ((row & 7) << 3))];
      }
#pragma unroll
      for (int mi = 0; mi < 4; ++mi)
#pragma unroll
        for (int ni = 0; ni < 2; ++ni)
          acc[mi][ni] = mfma16(af[mi], bf[ni], acc[mi][ni]);
    }
    __syncthreads();
  }

  float colacc[2] = {0.f, 0.f};
#pragma unroll
  for (int mi = 0; mi < 4; ++mi) {
#pragma unroll
    for (int ni = 0; ni < 2; ++ni) {
#pragma unroll
      for (int j = 0; j < 4; ++j) {
        int rowg = bm * 128 + wr * 64 + mi * 16 + g * 4 + j;
        int colg = bn * 64 + wc * 32 + ni * 16 + c;
        float val = fmaf(bias[colg], bscale, acc[mi][ni][j]);
        if (CMODE == 0) {
          int b = rowg >> 11, s = rowg & (S - 1);
          int h = colg >> 6, d = colg & 63;
          if (kswz) d ^= (s & 7) << 3;   // bake attn K-staging swizzle (rows pre-compacted)
          ((u16*)Cout)[((size_t)((b * HN + h) * S + s)) * 64 + d] = f2b(val);
        } else if (CMODE == 1) {
          ((float*)Cout)[(size_t)rowg * N + colg] = val;
        } else {
          // V path: transpose into vTc[bh*64+dv][*] with compacted key permute+swizzle
          int b = rowg >> 11, s = rowg & (S - 1);
          int h = colg >> 6, dv = colg & 63;
          colacc[ni] += val;
          int ck = posT[(b << 11) | s];
          int ti = ck >> 6, jl = ck & 63;
          // key jl = 32a+16b'+8cc+4d+e -> slot 32a+16cc+8d+4b'+e
          int slot = (jl & 35) | ((jl & 8) << 1) | ((jl & 4) << 1) | ((jl & 16) >> 2);
          int colv = slot ^ ((dv & 7) << 3);
          ((u16*)Cout)[((size_t)((b * HN + h) * 64 + dv)) * S + ti * 64 + colv] = f2b(val);
        }
      }
    }
  }
  if (CMODE == 2) {
#pragma unroll
    for (int ni = 0; ni < 2; ++ni) {
      float s_ = colacc[ni];
      s_ += __shfl_xor(s_, 16);
      s_ += __shfl_xor(s_, 32);
      if (lane < 16) {
        int colg = bn * 64 + wc * 32 + ni * 16 + c;
        int b = (bm * 128) >> 11;
        atomicAdd(&csum[b * 1024 + colg], s_);
      }
    }
  }
}

// QKV projection from bf16 copies (K input row-compacted); 1536 blocks, XCD-chunked.
// V path writes the transposed/permuted/swizzled vTc directly + column sums.
__global__ __launch_bounds__(256) void qkv_gemm(
    const u16* __restrict__ Abase, const u16* __restrict__ WTbase,
    const float* __restrict__ b0, const float* __restrict__ b1, const float* __restrict__ b2,
    u16* __restrict__ qb, u16* __restrict__ kc, u16* __restrict__ vTc,
    const int* __restrict__ eqt, const u16* __restrict__ posT,
    float* __restrict__ colsumg)
{
  __shared__ __align__(16) u16 As[128 * 64];
  __shared__ __align__(16) u16 Bs[64 * 64];
  const int bid = blockIdx.x;
  const int l = (bid & 7) * 192 + (bid >> 3);
  const int z = l >> 9, rem = l & 511, bm = rem >> 4, bn = rem & 15;
  const u16* A = Abase + (size_t)z * (4u << 20);
  const u16* Bt = WTbase + (size_t)z * (1u << 20);
  if (z == 0) {
    gemm_core<0>(As, Bs, A, Bt, b0, qb, 1024, 1024, bn, bm, QSCALE, 0, nullptr, nullptr);
  } else if (z == 1) {
    int b_ = (bm * 128) >> 11;
    int cnt_ = eqt[b_ * 32 + 31];
    if (((bm * 128) & 2047) >= cnt_) return;    // whole block in masked tail: skip
    gemm_core<0>(As, Bs, A, Bt, b1, kc, 1024, 1024, bn, bm, 1.0f, 1, nullptr, nullptr);
  } else {
    gemm_core<2>(As, Bs, A, Bt, b2, vTc, 1024, 1024, bn, bm, 1.0f, 0, posT, colsumg);
  }
}

__global__ __launch_bounds__(256) void out_gemm(
    const u16* __restrict__ Av, const u16* __restrict__ Bt,
    const float* __restrict__ bias, void* __restrict__ Cout)
{
  __shared__ __align__(16) u16 As[128 * 64];
  __shared__ __align__(16) u16 Bs[64 * 64];
  const int bid = blockIdx.x;
  const int l = (bid & 7) * 64 + (bid >> 3);
  const int bm = l >> 4, bn = l & 15;
  gemm_core<1>(As, Bs, Av, Bt, bias, Cout, 1024, 1024, bn, bm, 1.0f,
               0, nullptr, nullptr);
}

// ---------------- flash attention: compacted keys (QBLK=64, 1024 blocks) ----------
__global__ __launch_bounds__(256) void attn_kernel(
    const u16* __restrict__ q, const u16* __restrict__ kc,
    const u16* __restrict__ vTc, const u16* __restrict__ idxc,
    const int* __restrict__ eqt, const float* __restrict__ colsumg,
    u16* __restrict__ ao)
{
  __shared__ __align__(16) u16 Ks[2][64 * 64];
  __shared__ __align__(16) u16 Vs[2][64 * 64];

  const int tid = threadIdx.x;
  const int wid = tid >> 6, lane = tid & 63;
  const int g = lane >> 4, c = lane & 15;
  const int i = blockIdx.x;
  const int qt = 31 - (i >> 5);     // LPT: longest blocks dispatch first
  const int bh = i & 31;
  const int b = bh >> 4, h = bh & 15;

  const u16* idxb = idxc + b * 2048;
  const int ecnt = eqt[b * 32 + qt];
  const int nt = (ecnt + 63) >> 6;
  const int fz = idxb[0];
  const int qbasew = qt * 64 + wid * 16;
  const int qrow = qbasew + c;

  bfrag qf[2];
#pragma unroll
  for (int ks = 0; ks < 2; ++ks)
    qf[ks] = *(const bfrag*)&q[((size_t)bh * S + qrow) * 64 + ks * 32 + g * 8];

  float m = -3.0e38f, lsum = 0.f;
  f32x4 acc[4] = {};

  const size_t kbase = (size_t)bh * S * 64;
  const size_t vbase = (size_t)bh * 64 * S;
  const int sb = wid * 2048 + (lane << 4);
  const int sb2 = sb + 1024;

#define STAGE(buf, t)                                                              \
  do {                                                                             \
    gload_lds16(&kc[kbase + (size_t)(t) * 4096 + (sb >> 1)],                       \
                (char*)Ks[buf] + wid * 2048);                                      \
    gload_lds16(&kc[kbase + (size_t)(t) * 4096 + (sb2 >> 1)],                      \
                (char*)Ks[buf] + wid * 2048 + 1024);                               \
    gload_lds16(&vTc[vbase + (size_t)(sb >> 7) * S + (t) * 64 + ((sb & 127) >> 1)],\
                (char*)Vs[buf] + wid * 2048);                                      \
    gload_lds16(&vTc[vbase + (size_t)(sb2 >> 7) * S + (t) * 64 + ((sb2 & 127) >> 1)],\
                (char*)Vs[buf] + wid * 2048 + 1024);                               \
  } while (0)

  if (nt > 0) {
    STAGE(0, 0);
    __syncthreads();

    int cur = 0;
    for (int t = 0; t < nt; ++t) {
      if (t + 1 < nt) { STAGE(cur ^ 1, t + 1); }

      f32x4 sc[4] = {};
      __builtin_amdgcn_s_setprio(1);
#pragma unroll
      for (int ks = 0; ks < 2; ++ks)
#pragma unroll
        for (int nf = 0; nf < 4; ++nf) {
          int row = nf * 16 + c;
          bfrag kf = *(const bfrag*)&Ks[cur][row * 64 + ((ks * 32 + g * 8) ^ ((row & 7) << 3))];
          sc[nf] = mfma16(kf, qf[ks], sc[nf]);
        }
      __builtin_amdgcn_s_setprio(0);

      float sval[4][4];
#pragma unroll
      for (int nf = 0; nf < 4; ++nf)
#pragma unroll
        for (int r = 0; r < 4; ++r) sval[nf][r] = sc[nf][r];

      if ((int)idxb[t * 64 + 63] > qbasew) {
#pragma unroll
        for (int nf = 0; nf < 4; ++nf)
#pragma unroll
          for (int r = 0; r < 4; ++r) {
            int ov = idxb[t * 64 + nf * 16 + g * 4 + r];
            if (ov > qrow) sval[nf][r] = NBIG;
          }
      }

      float pm = sval[0][0];
#pragma unroll
      for (int nf = 0; nf < 4; ++nf)
#pragma unroll
        for (int r = 0; r < 4; ++r) pm = fmaxf(pm, sval[nf][r]);
      pm = fmaxf(pm, __shfl_xor(pm, 16));
      pm = fmaxf(pm, __shfl_xor(pm, 32));
      if (!__all(pm - m <= 11.5416f)) {   // defer-max
        float mn = fmaxf(m, pm);
        float fac = fexp2(m - mn);
        lsum *= fac;
#pragma unroll
        for (int nf = 0; nf < 4; ++nf)
#pragma unroll
          for (int j = 0; j < 4; ++j) acc[nf][j] *= fac;
        m = mn;
      }
      float p16v[4][4];
      float rs = 0.f;
#pragma unroll
      for (int nf = 0; nf < 4; ++nf)
#pragma unroll
        for (int r = 0; r < 4; ++r) {
          float pv = fexp2(sval[nf][r] - m);
          p16v[nf][r] = pv;
          rs += pv;
        }
      rs += __shfl_xor(rs, 16);
      rs += __shfl_xor(rs, 32);
      lsum += rs;

      bfrag pa[2];
#pragma unroll
      for (int ks = 0; ks < 2; ++ks) {
        union { u32 w[4]; bfrag f; } pu;
#pragma unroll
        for (int tt = 0; tt < 4; ++tt)
          pu.w[tt] = cvtpk(p16v[2 * ks + (tt >> 1)][2 * (tt & 1)],
                           p16v[2 * ks + (tt >> 1)][2 * (tt & 1) + 1]);
        pa[ks] = pu.f;
      }

      __builtin_amdgcn_s_setprio(1);
#pragma unroll
      for (int ks = 0; ks < 2; ++ks)
#pragma unroll
        for (int nf = 0; nf < 4; ++nf) {
          int row = nf * 16 + c;
          bfrag vf = *(const bfrag*)&Vs[cur][row * 64 + ((ks * 32 + g * 8) ^ ((row & 7) << 3))];
          acc[nf] = mfma16(vf, pa[ks], acc[nf]);
        }
      __builtin_amdgcn_s_setprio(0);

      __syncthreads();
      cur ^= 1;
    }
  }
#undef STAGE

  const float inv = 1.f / lsum;
#pragma unroll
  for (int nf = 0; nf < 4; ++nf) {
    u16x4 ov;
    if (qrow < fz) {
#pragma unroll
      for (int j = 0; j < 4; ++j)
        ov[j] = f2b(colsumg[bh * 64 + nf * 16 + g * 4 + j] * (1.f / 2048.f));
    } else {
#pragma unroll
      for (int j = 0; j < 4; ++j) ov[j] = f2b(acc[nf][j] * inv);
    }
    *(u16x4*)&ao[((size_t)b * S + qrow) * 1024 + h * 64 + nf * 16 + g * 4] = ov;
  }
}

// ---------------- launch ----------------
extern "C" void kernel_launch(void* const* d_in, const int* in_sizes, int n_in,
                              void* d_out, int out_size, void* d_ws, size_t ws_size,
                              hipStream_t stream)
{
  const float* Q  = (const float*)d_in[0];
  const float* Kk = (const float*)d_in[1];
  const float* V  = (const float*)d_in[2];
  const int* pad  = (const int*)d_in[3];
  const float* Wq = (const float*)d_in[4];
  const float* bq = (const float*)d_in[5];
  const float* Wk = (const float*)d_in[6];
  const float* bk = (const float*)d_in[7];
  const float* Wv = (const float*)d_in[8];
  const float* bv = (const float*)d_in[9];
  const float* Wo = (const float*)d_in[10];
  const float* bo = (const float*)d_in[11];

  // ws layout (u16 elems): WT [0,4M) | q [4M,8M) | kc [8M,12M) | ao [12M,16M)
  // | vTc [16M,20M) | Abf [20M,32M) | tables [32M,..): colsumg f32[2048],
  // idxc u16[4096], posT u16[4096], eqt int[64]   (~64.1 MiB)
  u16* ws  = (u16*)d_ws;
  u16* WoT = ws + 3 * (size_t)(1u << 20);
  u16* qb  = ws + 4 * (size_t)(1u << 20);
  u16* kc  = ws + 8 * (size_t)(1u << 20);
  u16* ao  = ws + 12 * (size_t)(1u << 20);
  u16* vTc = ws + 16 * (size_t)(1u << 20);
  u16* Abf = ws + 20 * (size_t)(1u << 20);
  u16* tab = ws + 32 * (size_t)(1u << 20);
  float* colsumg = (float*)tab;                 // 2048 f32 = 4096 u16
  u16* idxc = tab + 4096;                       // 4096 u16
  u16* posT = tab + 8192;                       // 4096 u16
  int* eqt  = (int*)(tab + 12288);              // 64 int

  wtrans_kernel<<<dim3(16, 16, 5), 256, 0, stream>>>(Wq, Wk, Wv, Wo, ws,
                                                     pad, idxc, posT, eqt, colsumg);
  cvt_kernel<<<dim3(2048, 3), 256, 0, stream>>>(Q, Kk, V, posT, Abf);
  qkv_gemm<<<1536, 256, 0, stream>>>(Abf, ws, bq, bk, bv, qb, kc, vTc, eqt, posT, colsumg);
  attn_kernel<<<1024, 256, 0, stream>>>(qb, kc, vTc, idxc, eqt, colsumg, ao);
  out_gemm<<<512, 256, 0, stream>>>(ao, WoT, bo, d_out);
}

// Round 19
// 102.177 us; speedup vs baseline: 1.1646x; 1.1646x over previous
//
#include <hip/hip_runtime.h>

typedef unsigned short u16;
typedef unsigned int u32;

typedef __attribute__((ext_vector_type(8))) short bfrag;   // 8 bf16 for MFMA A/B
typedef __attribute__((ext_vector_type(4))) float f32x4;
typedef __attribute__((ext_vector_type(8))) u16 u16x8;
typedef __attribute__((ext_vector_type(4))) u16 u16x4;

constexpr int S = 2048;
constexpr int HN = 16;
constexpr float QSCALE = 0.18033688011112042f;  // 0.125 * log2(e)
constexpr float NBIG   = -1.442695e9f;          // -1e9 * log2(e)

__device__ __forceinline__ u16 f2b(float f) {
  u32 u = __builtin_bit_cast(u32, f);
  return (u16)((u + 0x7FFFu + ((u >> 16) & 1u)) >> 16);  // RNE f32->bf16
}
__device__ __forceinline__ float b2f(u16 v) {
  u32 u = (u32)v << 16;
  return __builtin_bit_cast(float, u);
}
__device__ __forceinline__ u32 cvtpk(float lo, float hi) {
  u32 d;
  asm("v_cvt_pk_bf16_f32 %0, %1, %2" : "=v"(d) : "v"(lo), "v"(hi));
  return d;
}
__device__ __forceinline__ float fexp2(float x) { return __builtin_amdgcn_exp2f(x); }

__device__ __forceinline__ f32x4 mfma16(bfrag a, bfrag b, f32x4 c) {
  return __builtin_amdgcn_mfma_f32_16x16x32_bf16(a, b, c, 0, 0, 0);
}

__device__ __forceinline__ void gload_lds16(const void* g, void* l) {
  __builtin_amdgcn_global_load_lds(
      (const __attribute__((address_space(1))) u32*)g,
      (__attribute__((address_space(3))) u32*)l, 16, 0, 0);
}

// ------ prefix scan of pad: compact indices, stable-partition perm, counts, zero colsum
__global__ __launch_bounds__(256) void pscan_kernel(
    const int* __restrict__ pad, u16* __restrict__ idxc, u16* __restrict__ posT,
    int* __restrict__ eqt, float* __restrict__ colsumg)
{
  __shared__ int wtot[4];
  __shared__ int cntS;
  const int b = blockIdx.x;
  const int t = threadIdx.x, lane = t & 63, w = t >> 6;
  for (int i = t; i < 1024; i += 256) colsumg[b * 1024 + i] = 0.f;
  int4 p0 = *(const int4*)&pad[b * 2048 + t * 8];
  int4 p1 = *(const int4*)&pad[b * 2048 + t * 8 + 4];
  int u[8] = {p0.x == 0, p0.y == 0, p0.z == 0, p0.w == 0,
              p1.x == 0, p1.y == 0, p1.z == 0, p1.w == 0};
  int ps[8], run = 0;
#pragma unroll
  for (int j = 0; j < 8; ++j) { run += u[j]; ps[j] = run; }
  int sc = run;
#pragma unroll
  for (int o = 1; o < 64; o <<= 1) {
    int v = __shfl_up(sc, o);
    if (lane >= o) sc += v;
  }
  if (lane == 63) wtot[w] = sc;
  __syncthreads();
  int base = 0;
#pragma unroll
  for (int i = 0; i < 4; ++i) if (i < w) base += wtot[i];
  int excl = base + sc - run;
#pragma unroll
  for (int j = 0; j < 8; ++j)
    if (u[j]) idxc[b * 2048 + excl + ps[j] - 1] = (u16)(t * 8 + j);
  if ((t & 7) == 7) eqt[b * 32 + (t >> 3)] = base + sc;
  if (t == 255) cntS = base + sc;
  __syncthreads();
  const int cnt = cntS;
#pragma unroll
  for (int j = 0; j < 8; ++j) {
    int e = t * 8 + j;
    int pv = u[j] ? (excl + ps[j] - 1) : (cnt + e - excl - ps[j]);
    posT[b * 2048 + e] = (u16)pv;
  }
  for (int j = cnt + t; j < 2048; j += 256) idxc[b * 2048 + j] = 0x7FFF;
}

// ------ fused prep: [0,1024) W transpose (+exp2 scale for Wq); [1024,7168) f32->bf16
// cvt of Q/K/V, K written ROW-COMPACTED via posT (masked K rows skipped entirely).
__global__ __launch_bounds__(256) void prep_kernel(
    const float* __restrict__ W0, const float* __restrict__ W1,
    const float* __restrict__ W2, const float* __restrict__ W3,
    u16* __restrict__ ws,
    const float* __restrict__ A0, const float* __restrict__ A1,
    const float* __restrict__ A2, const u16* __restrict__ posT,
    const int* __restrict__ eqt, u16* __restrict__ outbase)
{
  const int bid = blockIdx.x;
  const int t = threadIdx.x;

  if (bid >= 1024) {
    // ---- cvt path ----
    const int idx = bid - 1024;
    const int z = idx >> 11;
    const float* A = z == 0 ? A0 : z == 1 ? A1 : A2;
    u16* dst = outbase + (size_t)z * (4u << 20);
    const int row = (idx & 2047) * 2 + (t >> 7);
    const int col = (t & 127) * 8;
    int drow = row;
    if (z == 1) {
      int b = row >> 11;
      int p = posT[row];
      if (p >= eqt[b * 32 + 31]) return;   // masked K row: never read downstream
      drow = b * 2048 + p;
    }
    const float* src = &A[(size_t)row * 1024 + col];
    float4 v0 = *(const float4*)src;
    float4 v1 = *(const float4*)(src + 4);
    union { u32 w[4]; u16x8 v; } o;
    o.w[0] = cvtpk(v0.x, v0.y); o.w[1] = cvtpk(v0.z, v0.w);
    o.w[2] = cvtpk(v1.x, v1.y); o.w[3] = cvtpk(v1.z, v1.w);
    *(u16x8*)&dst[(size_t)drow * 1024 + col] = o.v;
    return;
  }

  // ---- W transpose path ----
  __shared__ u16 tile[64 * 65];
  const int z = bid >> 8, rem = bid & 255;
  const float* W = z == 0 ? W0 : z == 1 ? W1 : z == 2 ? W2 : W3;
  const float sc = z == 0 ? QSCALE : 1.0f;
  u16* WT = ws + (size_t)z * (1u << 20);
  const int k0 = (rem >> 4) * 64, n0 = (rem & 15) * 64;
#pragma unroll
  for (int i = 0; i < 4; ++i) {
    int idx = i * 256 + t;
    int r = idx >> 4, c4 = (idx & 15) * 4;
    float4 v = *(const float4*)&W[(size_t)(k0 + r) * 1024 + n0 + c4];
    tile[r * 65 + c4 + 0] = f2b(v.x * sc);
    tile[r * 65 + c4 + 1] = f2b(v.y * sc);
    tile[r * 65 + c4 + 2] = f2b(v.z * sc);
    tile[r * 65 + c4 + 3] = f2b(v.w * sc);
  }
  __syncthreads();
#pragma unroll
  for (int i = 0; i < 2; ++i) {
    int idx = i * 256 + t;
    int n = idx >> 3, k8 = (idx & 7) * 8;
    u16x8 o;
#pragma unroll
    for (int j = 0; j < 8; ++j) o[j] = tile[(k8 + j) * 65 + n];
    *(u16x8*)&WT[(size_t)(n0 + n) * 1024 + k0 + k8] = o;
  }
}

// -------- gather compacted V rows, transpose + permute + swizzle into vTc --------
__global__ __launch_bounds__(256) void vgather_kernel(
    const u16* __restrict__ vb, const u16* __restrict__ idxc, u16* __restrict__ vTc)
{
  __shared__ u16 tile[64 * 65];
  const int ti = blockIdx.x, bh = blockIdx.y, b = bh >> 4;
  const int t = threadIdx.x;
#pragma unroll
  for (int i = 0; i < 2; ++i) {
    int idx = i * 256 + t;
    int r = idx >> 3, c8 = (idx & 7) * 8;
    int o = idxc[b * 2048 + ti * 64 + r];
    u16x8 in = {};
    if (o != 0x7FFF) in = *(const u16x8*)&vb[((size_t)bh * 2048 + o) * 64 + c8];
#pragma unroll
    for (int j = 0; j < 8; ++j) tile[r * 65 + c8 + j] = in[j];
  }
  __syncthreads();
#pragma unroll
  for (int i = 0; i < 2; ++i) {
    int idx = i * 256 + t;
    int dv = idx >> 3, s8 = (idx & 7) * 8;
    u16x8 o_;
#pragma unroll
    for (int j = 0; j < 8; ++j) o_[j] = tile[(s8 + j) * 65 + dv];
    int a = s8 >> 5, bb = (s8 >> 4) & 1, cc = (s8 >> 3) & 1;
    int s0l = a * 32 + cc * 16 + bb * 4;
    int x = (dv & 7) << 3;
    u16x4 lo = {o_[0], o_[1], o_[2], o_[3]};
    u16x4 hi = {o_[4], o_[5], o_[6], o_[7]};
    size_t rowbase = ((size_t)bh * 64 + dv) * S + ti * 64;
    *(u16x4*)&vTc[rowbase + (s0l ^ x)] = lo;
    *(u16x4*)&vTc[rowbase + ((s0l + 8) ^ x)] = hi;
  }
}

// ------- shared GEMM core, 128(M) x 64(N) tile (two-barrier structure) ----------
template <int CMODE>
__device__ __forceinline__ void gemm_core(
    u16* As, u16* Bs,
    const u16* __restrict__ A, const u16* __restrict__ Bt,
    const float* __restrict__ bias, void* __restrict__ Cout,
    int N, int K, int bn, int bm, float bscale,
    int kswz, float* __restrict__ csum)
{
  const int tid = threadIdx.x;
  const int wid = tid >> 6, lane = tid & 63;
  const int g = lane >> 4, c = lane & 15;
  const int wr = wid >> 1, wc = wid & 1;

  f32x4 acc[4][2] = {};

  const int nkt = K >> 6;
  for (int kt = 0; kt < nkt; ++kt) {
#pragma unroll
    for (int p = 0; p < 4; ++p) {
      int off = (p * 4 + wid) * 1024 + (lane << 4);
      int row = off >> 7, colb = off & 127;
      gload_lds16(&A[(size_t)(bm * 128 + row) * K + kt * 64 +
                     ((colb ^ ((row & 7) << 4)) >> 1)],
                  (char*)As + (p * 4 + wid) * 1024);
    }
#pragma unroll
    for (int p = 0; p < 2; ++p) {
      int off = (p * 4 + wid) * 1024 + (lane << 4);
      int row = off >> 7, colb = off & 127;
      gload_lds16(&Bt[(size_t)(bn * 64 + row) * K + kt * 64 +
                      ((colb ^ ((row & 7) << 4)) >> 1)],
                  (char*)Bs + (p * 4 + wid) * 1024);
    }
    __syncthreads();

#pragma unroll
    for (int ks = 0; ks < 2; ++ks) {
      bfrag af[4], bf[2];
#pragma unroll
      for (int mi = 0; mi < 4; ++mi) {
        int row = wr * 64 + mi * 16 + c;
        af[mi] = *(const bfrag*)&As[row * 64 + ((ks * 32 + g * 8) ^ ((row & 7) << 3))];
      }
#pragma unroll
      for (int ni = 0; ni < 2; ++ni) {
        int row = wc * 32 + ni * 16 + c;
        bf[ni] = *(const bfrag*)&Bs[row * 64 + ((ks * 32 + g * 8) ^ ((row & 7) << 3))];
      }
#pragma unroll
      for (int mi = 0; mi < 4; ++mi)
#pragma unroll
        for (int ni = 0; ni < 2; ++ni)
          acc[mi][ni] = mfma16(af[mi], bf[ni], acc[mi][ni]);
    }
    __syncthreads();
  }

  float colacc[2] = {0.f, 0.f};
#pragma unroll
  for (int mi = 0; mi < 4; ++mi) {
#pragma unroll
    for (int ni = 0; ni < 2; ++ni) {
#pragma unroll
      for (int j = 0; j < 4; ++j) {
        int rowg = bm * 128 + wr * 64 + mi * 16 + g * 4 + j;
        int colg = bn * 64 + wc * 32 + ni * 16 + c;
        float val = fmaf(bias[colg], bscale, acc[mi][ni][j]);
        if (CMODE == 0) {
          int b = rowg >> 11, s = rowg & (S - 1);
          int h = colg >> 6, d = colg & 63;
          if (kswz) d ^= (s & 7) << 3;   // bake attn K-staging swizzle (rows pre-compacted)
          if (csum) colacc[ni] += val;
          ((u16*)Cout)[((size_t)((b * HN + h) * S + s)) * 64 + d] = f2b(val);
        } else {
          ((float*)Cout)[(size_t)rowg * N + colg] = val;
        }
      }
    }
  }
  if (CMODE == 0 && csum) {
#pragma unroll
    for (int ni = 0; ni < 2; ++ni) {
      float s_ = colacc[ni];
      s_ += __shfl_xor(s_, 16);
      s_ += __shfl_xor(s_, 32);
      if (lane < 16) {
        int colg = bn * 64 + wc * 32 + ni * 16 + c;
        int b = (bm * 128) >> 11;
        atomicAdd(&csum[b * 1024 + colg], s_);
      }
    }
  }
}

// QKV projection from bf16 copies (K input row-compacted); 1536 blocks, XCD-chunked.
__global__ __launch_bounds__(256) void qkv_gemm(
    const u16* __restrict__ Abase, const u16* __restrict__ WTbase,
    const float* __restrict__ b0, const float* __restrict__ b1, const float* __restrict__ b2,
    u16* __restrict__ qb, u16* __restrict__ kc, u16* __restrict__ vb,
    const int* __restrict__ eqt, float* __restrict__ colsumg)
{
  __shared__ __align__(16) u16 As[128 * 64];
  __shared__ __align__(16) u16 Bs[64 * 64];
  const int bid = blockIdx.x;
  const int l = (bid & 7) * 192 + (bid >> 3);
  const int z = l >> 9, rem = l & 511, bm = rem >> 4, bn = rem & 15;
  if (z == 1) {
    int b_ = (bm * 128) >> 11;
    int cnt_ = eqt[b_ * 32 + 31];
    if (((bm * 128) & 2047) >= cnt_) return;    // whole block in masked tail: skip
  }
  const u16* A = Abase + (size_t)z * (4u << 20);
  const u16* Bt = WTbase + (size_t)z * (1u << 20);
  const float* bias = z == 0 ? b0 : z == 1 ? b1 : b2;
  u16* C = z == 0 ? qb : z == 1 ? kc : vb;
  gemm_core<0>(As, Bs, A, Bt, bias, C, 1024, 1024, bn, bm,
               z == 0 ? QSCALE : 1.0f,
               z == 1 ? 1 : 0,
               z == 2 ? colsumg : nullptr);
}

__global__ __launch_bounds__(256) void out_gemm(
    const u16* __restrict__ Av, const u16* __restrict__ Bt,
    const float* __restrict__ bias, void* __restrict__ Cout)
{
  __shared__ __align__(16) u16 As[128 * 64];
  __shared__ __align__(16) u16 Bs[64 * 64];
  const int bid = blockIdx.x;
  const int l = (bid & 7) * 64 + (bid >> 3);
  const int bm = l >> 4, bn = l & 15;
  gemm_core<1>(As, Bs, Av, Bt, bias, Cout, 1024, 1024, bn, bm, 1.0f,
               0, nullptr);
}

// ---------------- flash attention: compacted keys (QBLK=64, 1024 blocks) ----------
__global__ __launch_bounds__(256) void attn_kernel(
    const u16* __restrict__ q, const u16* __restrict__ kc,
    const u16* __restrict__ vTc, const u16* __restrict__ idxc,
    const int* __restrict__ eqt, const float* __restrict__ colsumg,
    u16* __restrict__ ao)
{
  __shared__ __align__(16) u16 Ks[2][64 * 64];
  __shared__ __align__(16) u16 Vs[2][64 * 64];

  const int tid = threadIdx.x;
  const int wid = tid >> 6, lane = tid & 63;
  const int g = lane >> 4, c = lane & 15;
  const int i = blockIdx.x;
  const int qt = 31 - (i >> 5);     // LPT: longest blocks dispatch first
  const int bh = i & 31;
  const int b = bh >> 4, h = bh & 15;

  const u16* idxb = idxc + b * 2048;
  const int ecnt = eqt[b * 32 + qt];
  const int nt = (ecnt + 63) >> 6;
  const int fz = idxb[0];
  const int qbasew = qt * 64 + wid * 16;
  const int qrow = qbasew + c;

  bfrag qf[2];
#pragma unroll
  for (int ks = 0; ks < 2; ++ks)
    qf[ks] = *(const bfrag*)&q[((size_t)bh * S + qrow) * 64 + ks * 32 + g * 8];

  float m = -3.0e38f, lsum = 0.f;
  f32x4 acc[4] = {};

  const size_t kbase = (size_t)bh * S * 64;
  const size_t vbase = (size_t)bh * 64 * S;
  const int sb = wid * 2048 + (lane << 4);
  const int sb2 = sb + 1024;

#define STAGE(buf, t)                                                              \
  do {                                                                             \
    gload_lds16(&kc[kbase + (size_t)(t) * 4096 + (sb >> 1)],                       \
                (char*)Ks[buf] + wid * 2048);                                      \
    gload_lds16(&kc[kbase + (size_t)(t) * 4096 + (sb2 >> 1)],                      \
                (char*)Ks[buf] + wid * 2048 + 1024);                               \
    gload_lds16(&vTc[vbase + (size_t)(sb >> 7) * S + (t) * 64 + ((sb & 127) >> 1)],\
                (char*)Vs[buf] + wid * 2048);                                      \
    gload_lds16(&vTc[vbase + (size_t)(sb2 >> 7) * S + (t) * 64 + ((sb2 & 127) >> 1)],\
                (char*)Vs[buf] + wid * 2048 + 1024);                               \
  } while (0)

  if (nt > 0) {
    STAGE(0, 0);
    __syncthreads();

    int cur = 0;
    for (int t = 0; t < nt; ++t) {
      if (t + 1 < nt) { STAGE(cur ^ 1, t + 1); }

      f32x4 sc[4] = {};
      __builtin_amdgcn_s_setprio(1);
#pragma unroll
      for (int ks = 0; ks < 2; ++ks)
#pragma unroll
        for (int nf = 0; nf < 4; ++nf) {
          int row = nf * 16 + c;
          bfrag kf = *(const bfrag*)&Ks[cur][row * 64 + ((ks * 32 + g * 8) ^ ((row & 7) << 3))];
          sc[nf] = mfma16(kf, qf[ks], sc[nf]);
        }
      __builtin_amdgcn_s_setprio(0);

      float sval[4][4];
#pragma unroll
      for (int nf = 0; nf < 4; ++nf)
#pragma unroll
        for (int r = 0; r < 4; ++r) sval[nf][r] = sc[nf][r];

      if ((int)idxb[t * 64 + 63] > qbasew) {
#pragma unroll
        for (int nf = 0; nf < 4; ++nf)
#pragma unroll
          for (int r = 0; r < 4; ++r) {
            int ov = idxb[t * 64 + nf * 16 + g * 4 + r];
            if (ov > qrow) sval[nf][r] = NBIG;
          }
      }

      float pm = sval[0][0];
#pragma unroll
      for (int nf = 0; nf < 4; ++nf)
#pragma unroll
        for (int r = 0; r < 4; ++r) pm = fmaxf(pm, sval[nf][r]);
      pm = fmaxf(pm, __shfl_xor(pm, 16));
      pm = fmaxf(pm, __shfl_xor(pm, 32));
      if (!__all(pm - m <= 11.5416f)) {   // defer-max
        float mn = fmaxf(m, pm);
        float fac = fexp2(m - mn);
        lsum *= fac;
#pragma unroll
        for (int nf = 0; nf < 4; ++nf)
#pragma unroll
          for (int j = 0; j < 4; ++j) acc[nf][j] *= fac;
        m = mn;
      }
      float p16v[4][4];
      float rs = 0.f;
#pragma unroll
      for (int nf = 0; nf < 4; ++nf)
#pragma unroll
        for (int r = 0; r < 4; ++r) {
          float pv = fexp2(sval[nf][r] - m);
          p16v[nf][r] = pv;
          rs += pv;
        }
      rs += __shfl_xor(rs, 16);
      rs += __shfl_xor(rs, 32);
      lsum += rs;

      bfrag pa[2];
#pragma unroll
      for (int ks = 0; ks < 2; ++ks) {
        union { u32 w[4]; bfrag f; } pu;
#pragma unroll
        for (int tt = 0; tt < 4; ++tt)
          pu.w[tt] = cvtpk(p16v[2 * ks + (tt >> 1)][2 * (tt & 1)],
                           p16v[2 * ks + (tt >> 1)][2 * (tt & 1) + 1]);
        pa[ks] = pu.f;
      }

      __builtin_amdgcn_s_setprio(1);
#pragma unroll
      for (int ks = 0; ks < 2; ++ks)
#pragma unroll
        for (int nf = 0; nf < 4; ++nf) {
          int row = nf * 16 + c;
          bfrag vf = *(const bfrag*)&Vs[cur][row * 64 + ((ks * 32 + g * 8) ^ ((row & 7) << 3))];
          acc[nf] = mfma16(vf, pa[ks], acc[nf]);
        }
      __builtin_amdgcn_s_setprio(0);

      __syncthreads();
      cur ^= 1;
    }
  }
#undef STAGE

  const float inv = 1.f / lsum;
#pragma unroll
  for (int nf = 0; nf < 4; ++nf) {
    u16x4 ov;
    if (qrow < fz) {
#pragma unroll
      for (int j = 0; j < 4; ++j)
        ov[j] = f2b(colsumg[bh * 64 + nf * 16 + g * 4 + j] * (1.f / 2048.f));
    } else {
#pragma unroll
      for (int j = 0; j < 4; ++j) ov[j] = f2b(acc[nf][j] * inv);
    }
    *(u16x4*)&ao[((size_t)b * S + qrow) * 1024 + h * 64 + nf * 16 + g * 4] = ov;
  }
}

// ---------------- launch ----------------
extern "C" void kernel_launch(void* const* d_in, const int* in_sizes, int n_in,
                              void* d_out, int out_size, void* d_ws, size_t ws_size,
                              hipStream_t stream)
{
  const float* Q  = (const float*)d_in[0];
  const float* Kk = (const float*)d_in[1];
  const float* V  = (const float*)d_in[2];
  const int* pad  = (const int*)d_in[3];
  const float* Wq = (const float*)d_in[4];
  const float* bq = (const float*)d_in[5];
  const float* Wk = (const float*)d_in[6];
  const float* bk = (const float*)d_in[7];
  const float* Wv = (const float*)d_in[8];
  const float* bv = (const float*)d_in[9];
  const float* Wo = (const float*)d_in[10];
  const float* bo = (const float*)d_in[11];

  // ws layout (u16 elems): WT [0,4M) | q [4M,8M) | kc [8M,12M) | v/ao [12M,16M)
  // | vTc [16M,20M) | Abf [20M,32M) | tables [32M,..): colsumg f32[2048],
  // idxc u16[4096], posT u16[4096], eqt int[64]   (~64.1 MiB)
  u16* ws  = (u16*)d_ws;
  u16* WoT = ws + 3 * (size_t)(1u << 20);
  u16* qb  = ws + 4 * (size_t)(1u << 20);
  u16* kc  = ws + 8 * (size_t)(1u << 20);
  u16* vb  = ws + 12 * (size_t)(1u << 20);
  u16* vTc = ws + 16 * (size_t)(1u << 20);
  u16* Abf = ws + 20 * (size_t)(1u << 20);
  u16* tab = ws + 32 * (size_t)(1u << 20);
  float* colsumg = (float*)tab;                 // 2048 f32 = 4096 u16
  u16* idxc = tab + 4096;                       // 4096 u16
  u16* posT = tab + 8192;                       // 4096 u16
  int* eqt  = (int*)(tab + 12288);              // 64 int
  u16* ao   = vb;                               // v dead after vgather (colsum in qkv)

  pscan_kernel<<<2, 256, 0, stream>>>(pad, idxc, posT, eqt, colsumg);
  prep_kernel<<<7168, 256, 0, stream>>>(Wq, Wk, Wv, Wo, ws, Q, Kk, V, posT, eqt, Abf);
  qkv_gemm<<<1536, 256, 0, stream>>>(Abf, ws, bq, bk, bv, qb, kc, vb, eqt, colsumg);
  vgather_kernel<<<dim3(32, 32), 256, 0, stream>>>(vb, idxc, vTc);
  attn_kernel<<<1024, 256, 0, stream>>>(qb, kc, vTc, idxc, eqt, colsumg, ao);
  out_gemm<<<512, 256, 0, stream>>>(ao, WoT, bo, d_out);
}

// Round 20
// 98.639 us; speedup vs baseline: 1.2064x; 1.0359x over previous
//
#include <hip/hip_runtime.h>

typedef unsigned short u16;
typedef unsigned int u32;

typedef __attribute__((ext_vector_type(8))) short bfrag;   // 8 bf16 for MFMA A/B
typedef __attribute__((ext_vector_type(4))) float f32x4;
typedef __attribute__((ext_vector_type(8))) u16 u16x8;
typedef __attribute__((ext_vector_type(4))) u16 u16x4;

constexpr int S = 2048;
constexpr int HN = 16;
constexpr float QSCALE = 0.18033688011112042f;  // 0.125 * log2(e)
constexpr float NBIG   = -1.442695e9f;          // -1e9 * log2(e)

__device__ __forceinline__ u16 f2b(float f) {
  u32 u = __builtin_bit_cast(u32, f);
  return (u16)((u + 0x7FFFu + ((u >> 16) & 1u)) >> 16);  // RNE f32->bf16
}
__device__ __forceinline__ float b2f(u16 v) {
  u32 u = (u32)v << 16;
  return __builtin_bit_cast(float, u);
}
__device__ __forceinline__ u32 cvtpk(float lo, float hi) {
  u32 d;
  asm("v_cvt_pk_bf16_f32 %0, %1, %2" : "=v"(d) : "v"(lo), "v"(hi));
  return d;
}
__device__ __forceinline__ float fexp2(float x) { return __builtin_amdgcn_exp2f(x); }

__device__ __forceinline__ f32x4 mfma16(bfrag a, bfrag b, f32x4 c) {
  return __builtin_amdgcn_mfma_f32_16x16x32_bf16(a, b, c, 0, 0, 0);
}

__device__ __forceinline__ void gload_lds16(const void* g, void* l) {
  __builtin_amdgcn_global_load_lds(
      (const __attribute__((address_space(1))) u32*)g,
      (__attribute__((address_space(3))) u32*)l, 16, 0, 0);
}

// ---- fused prep, 7170 blocks ----
// [0,1024): W transpose + f32->bf16 (+exp2 scale for Wq)
// [1024,7168): f32->bf16 cvt of Q/K/V; K rows written ROW-COMPACTED with a
//              block-local prefix scan of pad (no cross-kernel posT dependency)
// [7168,7170): full pad scan producing idxc/eqt (+ colsumg zeroing) for attn/qkv
__global__ __launch_bounds__(256) void prep_kernel(
    const float* __restrict__ W0, const float* __restrict__ W1,
    const float* __restrict__ W2, const float* __restrict__ W3,
    u16* __restrict__ ws,
    const float* __restrict__ A0, const float* __restrict__ A1,
    const float* __restrict__ A2, const int* __restrict__ pad,
    u16* __restrict__ idxc, int* __restrict__ eqt, float* __restrict__ colsumg,
    u16* __restrict__ outbase)
{
  const int bid = blockIdx.x;
  const int t = threadIdx.x;

  if (bid >= 7168) {
    // ---- table-producing pad scan (2 blocks) ----
    __shared__ int wtot[4];
    __shared__ int cntS;
    const int b = bid - 7168;
    const int lane = t & 63, w = t >> 6;
    for (int i = t; i < 1024; i += 256) colsumg[b * 1024 + i] = 0.f;
    int4 p0 = *(const int4*)&pad[b * 2048 + t * 8];
    int4 p1 = *(const int4*)&pad[b * 2048 + t * 8 + 4];
    int u[8] = {p0.x == 0, p0.y == 0, p0.z == 0, p0.w == 0,
                p1.x == 0, p1.y == 0, p1.z == 0, p1.w == 0};
    int ps[8], run = 0;
#pragma unroll
    for (int j = 0; j < 8; ++j) { run += u[j]; ps[j] = run; }
    int sc = run;
#pragma unroll
    for (int o = 1; o < 64; o <<= 1) {
      int v = __shfl_up(sc, o);
      if (lane >= o) sc += v;
    }
    if (lane == 63) wtot[w] = sc;
    __syncthreads();
    int base = 0;
#pragma unroll
    for (int i = 0; i < 4; ++i) if (i < w) base += wtot[i];
    int excl = base + sc - run;
#pragma unroll
    for (int j = 0; j < 8; ++j)
      if (u[j]) idxc[b * 2048 + excl + ps[j] - 1] = (u16)(t * 8 + j);
    if ((t & 7) == 7) eqt[b * 32 + (t >> 3)] = base + sc;
    if (t == 255) cntS = base + sc;
    __syncthreads();
    const int cnt = cntS;
    for (int j = cnt + t; j < 2048; j += 256) idxc[b * 2048 + j] = 0x7FFF;
    return;
  }

  if (bid >= 1024) {
    // ---- cvt path ----
    const int idx = bid - 1024;
    const int z = idx >> 11;
    const float* A = z == 0 ? A0 : z == 1 ? A1 : A2;
    u16* dst = outbase + (size_t)z * (4u << 20);
    const int row = (idx & 2047) * 2 + (t >> 7);
    const int col = (t & 127) * 8;
    int drow = row;
    if (z == 1) {
      // block-local compaction scan: positions for this block's two rows
      __shared__ int wtot[4];
      __shared__ int cntS;
      __shared__ int posS[2];
      const int b = row >> 11;
      const int lane = t & 63, w = t >> 6;
      const int e0 = ((idx & 2047) * 2) & 2047;   // local index of even row
      int4 p0 = *(const int4*)&pad[b * 2048 + t * 8];
      int4 p1 = *(const int4*)&pad[b * 2048 + t * 8 + 4];
      int u[8] = {p0.x == 0, p0.y == 0, p0.z == 0, p0.w == 0,
                  p1.x == 0, p1.y == 0, p1.z == 0, p1.w == 0};
      int ps[8], run = 0;
#pragma unroll
      for (int j = 0; j < 8; ++j) { run += u[j]; ps[j] = run; }
      int sc = run;
#pragma unroll
      for (int o = 1; o < 64; o <<= 1) {
        int v = __shfl_up(sc, o);
        if (lane >= o) sc += v;
      }
      if (lane == 63) wtot[w] = sc;
      __syncthreads();
      int base = 0;
#pragma unroll
      for (int i = 0; i < 4; ++i) if (i < w) base += wtot[i];
      int excl = base + sc - run;
      if (t == 255) cntS = base + sc;
      // the thread owning elements e0/e0+1 publishes their positions
      if ((t * 8) == (e0 & ~7)) {
        int j0 = e0 & 7;
#pragma unroll
        for (int j = 0; j < 8; ++j) {
          int pv = u[j] ? (excl + ps[j] - 1) : (0x7FFF);
          if (j == j0) posS[0] = pv;
          if (j == j0 + 1) posS[1] = pv;
        }
      }
      __syncthreads();
      const int cnt = cntS;
      int p = posS[t >> 7];
      if (p >= cnt) return;                 // masked K row: never read downstream
      drow = b * 2048 + p;
    }
    const float* src = &A[(size_t)row * 1024 + col];
    float4 v0 = *(const float4*)src;
    float4 v1 = *(const float4*)(src + 4);
    union { u32 w[4]; u16x8 v; } o;
    o.w[0] = cvtpk(v0.x, v0.y); o.w[1] = cvtpk(v0.z, v0.w);
    o.w[2] = cvtpk(v1.x, v1.y); o.w[3] = cvtpk(v1.z, v1.w);
    *(u16x8*)&dst[(size_t)drow * 1024 + col] = o.v;
    return;
  }

  // ---- W transpose path ----
  __shared__ u16 tile[64 * 65];
  const int z = bid >> 8, rem = bid & 255;
  const float* W = z == 0 ? W0 : z == 1 ? W1 : z == 2 ? W2 : W3;
  const float sc = z == 0 ? QSCALE : 1.0f;
  u16* WT = ws + (size_t)z * (1u << 20);
  const int k0 = (rem >> 4) * 64, n0 = (rem & 15) * 64;
#pragma unroll
  for (int i = 0; i < 4; ++i) {
    int idx = i * 256 + t;
    int r = idx >> 4, c4 = (idx & 15) * 4;
    float4 v = *(const float4*)&W[(size_t)(k0 + r) * 1024 + n0 + c4];
    tile[r * 65 + c4 + 0] = f2b(v.x * sc);
    tile[r * 65 + c4 + 1] = f2b(v.y * sc);
    tile[r * 65 + c4 + 2] = f2b(v.z * sc);
    tile[r * 65 + c4 + 3] = f2b(v.w * sc);
  }
  __syncthreads();
#pragma unroll
  for (int i = 0; i < 2; ++i) {
    int idx = i * 256 + t;
    int n = idx >> 3, k8 = (idx & 7) * 8;
    u16x8 o;
#pragma unroll
    for (int j = 0; j < 8; ++j) o[j] = tile[(k8 + j) * 65 + n];
    *(u16x8*)&WT[(size_t)(n0 + n) * 1024 + k0 + k8] = o;
  }
}

// -------- gather compacted V rows, transpose + permute + swizzle into vTc --------
__global__ __launch_bounds__(256) void vgather_kernel(
    const u16* __restrict__ vb, const u16* __restrict__ idxc, u16* __restrict__ vTc)
{
  __shared__ u16 tile[64 * 65];
  const int ti = blockIdx.x, bh = blockIdx.y, b = bh >> 4;
  const int t = threadIdx.x;
#pragma unroll
  for (int i = 0; i < 2; ++i) {
    int idx = i * 256 + t;
    int r = idx >> 3, c8 = (idx & 7) * 8;
    int o = idxc[b * 2048 + ti * 64 + r];
    u16x8 in = {};
    if (o != 0x7FFF) in = *(const u16x8*)&vb[((size_t)bh * 2048 + o) * 64 + c8];
#pragma unroll
    for (int j = 0; j < 8; ++j) tile[r * 65 + c8 + j] = in[j];
  }
  __syncthreads();
#pragma unroll
  for (int i = 0; i < 2; ++i) {
    int idx = i * 256 + t;
    int dv = idx >> 3, s8 = (idx & 7) * 8;
    u16x8 o_;
#pragma unroll
    for (int j = 0; j < 8; ++j) o_[j] = tile[(s8 + j) * 65 + dv];
    int a = s8 >> 5, bb = (s8 >> 4) & 1, cc = (s8 >> 3) & 1;
    int s0l = a * 32 + cc * 16 + bb * 4;
    int x = (dv & 7) << 3;
    u16x4 lo = {o_[0], o_[1], o_[2], o_[3]};
    u16x4 hi = {o_[4], o_[5], o_[6], o_[7]};
    size_t rowbase = ((size_t)bh * 64 + dv) * S + ti * 64;
    *(u16x4*)&vTc[rowbase + (s0l ^ x)] = lo;
    *(u16x4*)&vTc[rowbase + ((s0l + 8) ^ x)] = hi;
  }
}

// ------- shared GEMM core, 128(M) x 64(N) tile (two-barrier structure) ----------
template <int CMODE>
__device__ __forceinline__ void gemm_core(
    u16* As, u16* Bs,
    const u16* __restrict__ A, const u16* __restrict__ Bt,
    const float* __restrict__ bias, void* __restrict__ Cout,
    int N, int K, int bn, int bm, float bscale,
    int kswz, float* __restrict__ csum)
{
  const int tid = threadIdx.x;
  const int wid = tid >> 6, lane = tid & 63;
  const int g = lane >> 4, c = lane & 15;
  const int wr = wid >> 1, wc = wid & 1;

  f32x4 acc[4][2] = {};

  const int nkt = K >> 6;
  for (int kt = 0; kt < nkt; ++kt) {
#pragma unroll
    for (int p = 0; p < 4; ++p) {
      int off = (p * 4 + wid) * 1024 + (lane << 4);
      int row = off >> 7, colb = off & 127;
      gload_lds16(&A[(size_t)(bm * 128 + row) * K + kt * 64 +
                     ((colb ^ ((row & 7) << 4)) >> 1)],
                  (char*)As + (p * 4 + wid) * 1024);
    }
#pragma unroll
    for (int p = 0; p < 2; ++p) {
      int off = (p * 4 + wid) * 1024 + (lane << 4);
      int row = off >> 7, colb = off & 127;
      gload_lds16(&Bt[(size_t)(bn * 64 + row) * K + kt * 64 +
                      ((colb ^ ((row & 7) << 4)) >> 1)],
                  (char*)Bs + (p * 4 + wid) * 1024);
    }
    __syncthreads();

#pragma unroll
    for (int ks = 0; ks < 2; ++ks) {
      bfrag af[4], bf[2];
#pragma unroll
      for (int mi = 0; mi < 4; ++mi) {
        int row = wr * 64 + mi * 16 + c;
        af[mi] = *(const bfrag*)&As[row * 64 + ((ks * 32 + g * 8) ^ ((row & 7) << 3))];
      }
#pragma unroll
      for (int ni = 0; ni < 2; ++ni) {
        int row = wc * 32 + ni * 16 + c;
        bf[ni] = *(const bfrag*)&Bs[row * 64 + ((ks * 32 + g * 8) ^ ((row & 7) << 3))];
      }
#pragma unroll
      for (int mi = 0; mi < 4; ++mi)
#pragma unroll
        for (int ni = 0; ni < 2; ++ni)
          acc[mi][ni] = mfma16(af[mi], bf[ni], acc[mi][ni]);
    }
    __syncthreads();
  }

  float colacc[2] = {0.f, 0.f};
#pragma unroll
  for (int mi = 0; mi < 4; ++mi) {
#pragma unroll
    for (int ni = 0; ni < 2; ++ni) {
#pragma unroll
      for (int j = 0; j < 4; ++j) {
        int rowg = bm * 128 + wr * 64 + mi * 16 + g * 4 + j;
        int colg = bn * 64 + wc * 32 + ni * 16 + c;
        float val = fmaf(bias[colg], bscale, acc[mi][ni][j]);
        if (CMODE == 0) {
          int b = rowg >> 11, s = rowg & (S - 1);
          int h = colg >> 6, d = colg & 63;
          if (kswz) d ^= (s & 7) << 3;   // bake attn K-staging swizzle (rows pre-compacted)
          if (csum) colacc[ni] += val;
          ((u16*)Cout)[((size_t)((b * HN + h) * S + s)) * 64 + d] = f2b(val);
        } else {
          ((float*)Cout)[(size_t)rowg * N + colg] = val;
        }
      }
    }
  }
  if (CMODE == 0 && csum) {
#pragma unroll
    for (int ni = 0; ni < 2; ++ni) {
      float s_ = colacc[ni];
      s_ += __shfl_xor(s_, 16);
      s_ += __shfl_xor(s_, 32);
      if (lane < 16) {
        int colg = bn * 64 + wc * 32 + ni * 16 + c;
        int b = (bm * 128) >> 11;
        atomicAdd(&csum[b * 1024 + colg], s_);
      }
    }
  }
}

// QKV projection from bf16 copies (K input row-compacted); 1536 blocks, XCD-chunked.
__global__ __launch_bounds__(256) void qkv_gemm(
    const u16* __restrict__ Abase, const u16* __restrict__ WTbase,
    const float* __restrict__ b0, const float* __restrict__ b1, const float* __restrict__ b2,
    u16* __restrict__ qb, u16* __restrict__ kc, u16* __restrict__ vb,
    const int* __restrict__ eqt, float* __restrict__ colsumg)
{
  __shared__ __align__(16) u16 As[128 * 64];
  __shared__ __align__(16) u16 Bs[64 * 64];
  const int bid = blockIdx.x;
  const int l = (bid & 7) * 192 + (bid >> 3);
  const int z = l >> 9, rem = l & 511, bm = rem >> 4, bn = rem & 15;
  if (z == 1) {
    int b_ = (bm * 128) >> 11;
    int cnt_ = eqt[b_ * 32 + 31];
    if (((bm * 128) & 2047) >= cnt_) return;    // whole block in masked tail: skip
  }
  const u16* A = Abase + (size_t)z * (4u << 20);
  const u16* Bt = WTbase + (size_t)z * (1u << 20);
  const float* bias = z == 0 ? b0 : z == 1 ? b1 : b2;
  u16* C = z == 0 ? qb : z == 1 ? kc : vb;
  gemm_core<0>(As, Bs, A, Bt, bias, C, 1024, 1024, bn, bm,
               z == 0 ? QSCALE : 1.0f,
               z == 1 ? 1 : 0,
               z == 2 ? colsumg : nullptr);
}

__global__ __launch_bounds__(256) void out_gemm(
    const u16* __restrict__ Av, const u16* __restrict__ Bt,
    const float* __restrict__ bias, void* __restrict__ Cout)
{
  __shared__ __align__(16) u16 As[128 * 64];
  __shared__ __align__(16) u16 Bs[64 * 64];
  const int bid = blockIdx.x;
  const int l = (bid & 7) * 64 + (bid >> 3);
  const int bm = l >> 4, bn = l & 15;
  gemm_core<1>(As, Bs, Av, Bt, bias, Cout, 1024, 1024, bn, bm, 1.0f,
               0, nullptr);
}

// ---------------- flash attention: compacted keys (QBLK=64, 1024 blocks) ----------
__global__ __launch_bounds__(256) void attn_kernel(
    const u16* __restrict__ q, const u16* __restrict__ kc,
    const u16* __restrict__ vTc, const u16* __restrict__ idxc,
    const int* __restrict__ eqt, const float* __restrict__ colsumg,
    u16* __restrict__ ao)
{
  __shared__ __align__(16) u16 Ks[2][64 * 64];
  __shared__ __align__(16) u16 Vs[2][64 * 64];

  const int tid = threadIdx.x;
  const int wid = tid >> 6, lane = tid & 63;
  const int g = lane >> 4, c = lane & 15;
  const int i = blockIdx.x;
  const int qt = 31 - (i >> 5);     // LPT: longest blocks dispatch first
  const int bh = i & 31;
  const int b = bh >> 4, h = bh & 15;

  const u16* idxb = idxc + b * 2048;
  const int ecnt = eqt[b * 32 + qt];
  const int nt = (ecnt + 63) >> 6;
  const int fz = idxb[0];
  const int qbasew = qt * 64 + wid * 16;
  const int qrow = qbasew + c;

  bfrag qf[2];
#pragma unroll
  for (int ks = 0; ks < 2; ++ks)
    qf[ks] = *(const bfrag*)&q[((size_t)bh * S + qrow) * 64 + ks * 32 + g * 8];

  float m = -3.0e38f, lsum = 0.f;
  f32x4 acc[4] = {};

  const size_t kbase = (size_t)bh * S * 64;
  const size_t vbase = (size_t)bh * 64 * S;
  const int sb = wid * 2048 + (lane << 4);
  const int sb2 = sb + 1024;

#define STAGE(buf, t)                                                              \
  do {                                                                             \
    gload_lds16(&kc[kbase + (size_t)(t) * 4096 + (sb >> 1)],                       \
                (char*)Ks[buf] + wid * 2048);                                      \
    gload_lds16(&kc[kbase + (size_t)(t) * 4096 + (sb2 >> 1)],                      \
                (char*)Ks[buf] + wid * 2048 + 1024);                               \
    gload_lds16(&vTc[vbase + (size_t)(sb >> 7) * S + (t) * 64 + ((sb & 127) >> 1)],\
                (char*)Vs[buf] + wid * 2048);                                      \
    gload_lds16(&vTc[vbase + (size_t)(sb2 >> 7) * S + (t) * 64 + ((sb2 & 127) >> 1)],\
                (char*)Vs[buf] + wid * 2048 + 1024);                               \
  } while (0)

  if (nt > 0) {
    STAGE(0, 0);
    __syncthreads();

    int cur = 0;
    for (int t = 0; t < nt; ++t) {
      if (t + 1 < nt) { STAGE(cur ^ 1, t + 1); }

      f32x4 sc[4] = {};
      __builtin_amdgcn_s_setprio(1);
#pragma unroll
      for (int ks = 0; ks < 2; ++ks)
#pragma unroll
        for (int nf = 0; nf < 4; ++nf) {
          int row = nf * 16 + c;
          bfrag kf = *(const bfrag*)&Ks[cur][row * 64 + ((ks * 32 + g * 8) ^ ((row & 7) << 3))];
          sc[nf] = mfma16(kf, qf[ks], sc[nf]);
        }
      __builtin_amdgcn_s_setprio(0);

      float sval[4][4];
#pragma unroll
      for (int nf = 0; nf < 4; ++nf)
#pragma unroll
        for (int r = 0; r < 4; ++r) sval[nf][r] = sc[nf][r];

      if ((int)idxb[t * 64 + 63] > qbasew) {
#pragma unroll
        for (int nf = 0; nf < 4; ++nf)
#pragma unroll
          for (int r = 0; r < 4; ++r) {
            int ov = idxb[t * 64 + nf * 16 + g * 4 + r];
            if (ov > qrow) sval[nf][r] = NBIG;
          }
      }

      float pm = sval[0][0];
#pragma unroll
      for (int nf = 0; nf < 4; ++nf)
#pragma unroll
        for (int r = 0; r < 4; ++r) pm = fmaxf(pm, sval[nf][r]);
      pm = fmaxf(pm, __shfl_xor(pm, 16));
      pm = fmaxf(pm, __shfl_xor(pm, 32));
      if (!__all(pm - m <= 11.5416f)) {   // defer-max
        float mn = fmaxf(m, pm);
        float fac = fexp2(m - mn);
        lsum *= fac;
#pragma unroll
        for (int nf = 0; nf < 4; ++nf)
#pragma unroll
          for (int j = 0; j < 4; ++j) acc[nf][j] *= fac;
        m = mn;
      }
      float p16v[4][4];
      float rs = 0.f;
#pragma unroll
      for (int nf = 0; nf < 4; ++nf)
#pragma unroll
        for (int r = 0; r < 4; ++r) {
          float pv = fexp2(sval[nf][r] - m);
          p16v[nf][r] = pv;
          rs += pv;
        }
      rs += __shfl_xor(rs, 16);
      rs += __shfl_xor(rs, 32);
      lsum += rs;

      bfrag pa[2];
#pragma unroll
      for (int ks = 0; ks < 2; ++ks) {
        union { u32 w[4]; bfrag f; } pu;
#pragma unroll
        for (int tt = 0; tt < 4; ++tt)
          pu.w[tt] = cvtpk(p16v[2 * ks + (tt >> 1)][2 * (tt & 1)],
                           p16v[2 * ks + (tt >> 1)][2 * (tt & 1) + 1]);
        pa[ks] = pu.f;
      }

      __builtin_amdgcn_s_setprio(1);
#pragma unroll
      for (int ks = 0; ks < 2; ++ks)
#pragma unroll
        for (int nf = 0; nf < 4; ++nf) {
          int row = nf * 16 + c;
          bfrag vf = *(const bfrag*)&Vs[cur][row * 64 + ((ks * 32 + g * 8) ^ ((row & 7) << 3))];
          acc[nf] = mfma16(vf, pa[ks], acc[nf]);
        }
      __builtin_amdgcn_s_setprio(0);

      __syncthreads();
      cur ^= 1;
    }
  }
#undef STAGE

  const float inv = 1.f / lsum;
#pragma unroll
  for (int nf = 0; nf < 4; ++nf) {
    u16x4 ov;
    if (qrow < fz) {
#pragma unroll
      for (int j = 0; j < 4; ++j)
        ov[j] = f2b(colsumg[bh * 64 + nf * 16 + g * 4 + j] * (1.f / 2048.f));
    } else {
#pragma unroll
      for (int j = 0; j < 4; ++j) ov[j] = f2b(acc[nf][j] * inv);
    }
    *(u16x4*)&ao[((size_t)b * S + qrow) * 1024 + h * 64 + nf * 16 + g * 4] = ov;
  }
}

// ---------------- launch ----------------
extern "C" void kernel_launch(void* const* d_in, const int* in_sizes, int n_in,
                              void* d_out, int out_size, void* d_ws, size_t ws_size,
                              hipStream_t stream)
{
  const float* Q  = (const float*)d_in[0];
  const float* Kk = (const float*)d_in[1];
  const float* V  = (const float*)d_in[2];
  const int* pad  = (const int*)d_in[3];
  const float* Wq = (const float*)d_in[4];
  const float* bq = (const float*)d_in[5];
  const float* Wk = (const float*)d_in[6];
  const float* bk = (const float*)d_in[7];
  const float* Wv = (const float*)d_in[8];
  const float* bv = (const float*)d_in[9];
  const float* Wo = (const float*)d_in[10];
  const float* bo = (const float*)d_in[11];

  // ws layout (u16 elems): WT [0,4M) | q [4M,8M) | kc [8M,12M) | v/ao [12M,16M)
  // | vTc [16M,20M) | Abf [20M,32M) | tables [32M,..): colsumg f32[2048],
  // idxc u16[4096], eqt int[64]   (~64.1 MiB)
  u16* ws  = (u16*)d_ws;
  u16* WoT = ws + 3 * (size_t)(1u << 20);
  u16* qb  = ws + 4 * (size_t)(1u << 20);
  u16* kc  = ws + 8 * (size_t)(1u << 20);
  u16* vb  = ws + 12 * (size_t)(1u << 20);
  u16* vTc = ws + 16 * (size_t)(1u << 20);
  u16* Abf = ws + 20 * (size_t)(1u << 20);
  u16* tab = ws + 32 * (size_t)(1u << 20);
  float* colsumg = (float*)tab;                 // 2048 f32 = 4096 u16
  u16* idxc = tab + 4096;                       // 4096 u16
  int* eqt  = (int*)(tab + 8192);               // 64 int
  u16* ao   = vb;                               // v dead after vgather (colsum in qkv)

  prep_kernel<<<7170, 256, 0, stream>>>(Wq, Wk, Wv, Wo, ws, Q, Kk, V, pad,
                                        idxc, eqt, colsumg, Abf);
  qkv_gemm<<<1536, 256, 0, stream>>>(Abf, ws, bq, bk, bv, qb, kc, vb, eqt, colsumg);
  vgather_kernel<<<dim3(32, 32), 256, 0, stream>>>(vb, idxc, vTc);
  attn_kernel<<<1024, 256, 0, stream>>>(qb, kc, vTc, idxc, eqt, colsumg, ao);
  out_gemm<<<512, 256, 0, stream>>>(ao, WoT, bo, d_out);
}